// Round 10
// baseline (78.794 us; speedup 1.0000x reference)
//
#include <hip/hip_runtime.h>

// ---------------- problem constants ----------------
#define NFFT    2048
#define HOPSZ   512
#define BATCH   8
#define TFRAMES 2048
#define FBINS   1025
#define OUTLEN  1048064           // HOP*(T-1)
#define TOTALP  1050112           // NFFT + HOP*(T-1)
#define MROWS   16384             // BATCH*TFRAMES

__device__ __forceinline__ unsigned short f2bf(float f) {
    unsigned u = __float_as_uint(f);
    u += 0x7fffu + ((u >> 16) & 1u);       // round-to-nearest-even
    return (unsigned short)(u >> 16);
}
__device__ __forceinline__ float bf2f(unsigned short h) {
    return __uint_as_float(((unsigned)h) << 16);
}

__device__ __forceinline__ float2 cmul(float2 a, float2 b) {
    return float2{a.x * b.x - a.y * b.y, a.x * b.y + a.y * b.x};
}
__device__ __forceinline__ float2 cadd(float2 a, float2 b) { return float2{a.x + b.x, a.y + b.y}; }
__device__ __forceinline__ float2 csub(float2 a, float2 b) { return float2{a.x - b.x, a.y - b.y}; }
__device__ __forceinline__ float2 cjmul(float2 a) { return float2{-a.y, a.x}; }   // i*a

// inverse DFT-4: y[r] = sum_j x[j] * i^{r j}
#define IDFT4(y0, y1, y2, y3, x0, x1, x2, x3) do {                         \
    float2 t0 = cadd(x0, x2), t1 = csub(x0, x2);                           \
    float2 t2 = cadd(x1, x3), t3 = cjmul(csub(x1, x3));                    \
    y0 = cadd(t0, t2); y2 = csub(t0, t2);                                  \
    y1 = cadd(t1, t3); y3 = csub(t1, t3); } while (0)

// inverse DFT-16 (radix-4 x radix-4, four-step): y[ra+4rb] = sum_j x[j] w16^{j(ra+4rb)}
__device__ __forceinline__ void idft16(float2* y, const float2* x) {
    const float C1 = 0.98078528040323044f, S1 = 0.19509032201612827f;   // unused names kept simple below
    (void)C1; (void)S1;
    const float c1 = 0.92387953251128674f, s1 = 0.38268343236508977f;   // cos/sin pi/8
    const float r2 = 0.70710678118654752f;
    float2 A[16];
    #pragma unroll
    for (int jb = 0; jb < 4; ++jb)
        IDFT4(A[jb * 4 + 0], A[jb * 4 + 1], A[jb * 4 + 2], A[jb * 4 + 3],
              x[jb], x[4 + jb], x[8 + jb], x[12 + jb]);
    // twiddle A[jb*4+ra] *= w16^{ra*jb}
    A[4 + 1]  = cmul(A[4 + 1],  float2{c1, s1});
    A[4 + 2]  = cmul(A[4 + 2],  float2{r2, r2});
    A[4 + 3]  = cmul(A[4 + 3],  float2{s1, c1});
    A[8 + 1]  = cmul(A[8 + 1],  float2{r2, r2});
    A[8 + 2]  = cjmul(A[8 + 2]);
    A[8 + 3]  = cmul(A[8 + 3],  float2{-r2, r2});
    A[12 + 1] = cmul(A[12 + 1], float2{s1, c1});
    A[12 + 2] = cmul(A[12 + 2], float2{-r2, r2});
    A[12 + 3] = cmul(A[12 + 3], float2{-c1, -s1});
    #pragma unroll
    for (int ra = 0; ra < 4; ++ra)
        IDFT4(y[ra], y[ra + 4], y[ra + 8], y[ra + 12],
              A[ra], A[4 + ra], A[8 + ra], A[12 + ra]);
}

// ---------------- window-pair table: wt[n] = (win[2n], win[2n+1]) -----------
__global__ void build_tabs(float2* __restrict__ wt) {
    int n = blockIdx.x * 256 + threadIdx.x;
    if (n < 1024)
        wt[n] = float2{0.5f - 0.5f * cospif((float)(2 * n)     * (1.0f / 1024.0f)),
                       0.5f - 0.5f * cospif((float)(2 * n + 1) * (1.0f / 1024.0f))};
}

// ---------------- per-frame irfft: wave-per-frame four-step register FFT ----
// 1024 = 16 x 64 Bailey four-step, inverse kernel W = e^{+2pi i/1024}:
//   F[n1+16(v1+16 v2)] : step1 lane k2 holds Z[64 k1+k2], idft16 over k1;
//   step2 *= W^{n1 k2}; transpose (LDS, chunk-rotated); step3 idft16 over c1
//   (k2 = 4 c1 + q), *= W64^{v1 q}; cross-lane idft4 over q via shfl_xor,
//   output lane group v2 = bitrev2(q). Verified analytically (DC + delta).
__global__ __launch_bounds__(256) void fft_frames(
    const float* __restrict__ re, const float* __restrict__ im,
    const float2* __restrict__ wt,
    unsigned short* __restrict__ Y)          // [BATCH][4][TOTALP] bf16
{
    __shared__ float2 tb[4][1024];           // 8KB per wave

    const int tid   = threadIdx.x;
    const int lane  = tid & 63;
    const int wv    = tid >> 6;
    const int frame = blockIdx.x * 4 + wv;
    const int b     = frame >> 11;
    const int t     = frame & (TFRAMES - 1);
    const float* rr = re + (size_t)frame * FBINS;
    const float* ii = im + (size_t)frame * FBINS;

    // per-lane twiddle bases (only transcendentals in the kernel)
    const float2 packb = float2{cospif((float)lane * (1.0f / 1024.0f)),
                                sinpif((float)lane * (1.0f / 1024.0f))};  // e^{i pi l/1024}
    const float2 base2 = cmul(packb, packb);                              // e^{2pi i l/1024}

    // e^{i pi k1/16}, k1 = 0..15 (compile-time immediates after unroll)
    const float wkc[16] = { 1.0f, 0.98078528040323044f, 0.92387953251128674f, 0.83146961230254524f,
                            0.70710678118654752f, 0.55557023301960222f, 0.38268343236508977f, 0.19509032201612827f,
                            0.0f, -0.19509032201612827f, -0.38268343236508977f, -0.55557023301960222f,
                            -0.70710678118654752f, -0.83146961230254524f, -0.92387953251128674f, -0.98078528040323044f };
    const float wks[16] = { 0.0f, 0.19509032201612827f, 0.38268343236508977f, 0.55557023301960222f,
                            0.70710678118654752f, 0.83146961230254524f, 0.92387953251128674f, 0.98078528040323044f,
                            1.0f, 0.98078528040323044f, 0.92387953251128674f, 0.83146961230254524f,
                            0.70710678118654752f, 0.55557023301960222f, 0.38268343236508977f, 0.19509032201612827f };

    // ---- pack: zz[k1] = Z[64*k1 + lane] ----
    float2 zz[16];
    #pragma unroll
    for (int k1 = 0; k1 < 16; ++k1) {
        const int m = 64 * k1 + lane;
        float Xr = rr[m],        Xi = ii[m];
        float Cr = rr[1024 - m], Ni = ii[1024 - m];
        float2 W = cmul(packb, float2{wkc[k1], wks[k1]});   // e^{i pi m/1024}
        float Er = Xr + Cr, Ei = Xi - Ni;
        float Or = Xr - Cr, Oi = Xi + Ni;
        float2 z = float2{Er - (W.x * Oi + W.y * Or), Ei + (W.x * Or - W.y * Oi)};
        if (k1 == 0 && lane == 0)                           // m == 0: im parts drop
            z = float2{Xr + Cr, Xr - Cr};
        zz[k1] = z;
    }

    // ---- step 1: A = idft16 over k1 ----
    float2 A[16];
    idft16(A, zz);

    // ---- step 2: A[n1] *= W1024^{n1*lane} (chained) ----
    {
        float2 w = base2;
        A[1] = cmul(A[1], w);
        #pragma unroll
        for (int n1 = 2; n1 < 16; ++n1) { w = cmul(w, base2); A[n1] = cmul(A[n1], w); }
    }

    // ---- transpose write: row=lane, 8 x float4, chunk-rotated ----
    {
        float4* rowp = (float4*)&tb[wv][lane * 16];
        #pragma unroll
        for (int j = 0; j < 8; ++j) {
            float2 e = A[2 * j], o = A[2 * j + 1];
            rowp[(j + lane) & 7] = float4{e.x, e.y, o.x, o.y};
        }
    }
    __syncthreads();   // safety (same-wave LDS dependence; single barrier in kernel)

    // ---- regroup read: lane = (q = lane>>4, n1r = lane&15); D[c1] = B[4c1+q][n1r]
    const int q   = lane >> 4;
    const int n1r = lane & 15;
    float2 D[16];
    #pragma unroll
    for (int c1 = 0; c1 < 16; ++c1) {
        const int row = 4 * c1 + q;
        D[c1] = tb[wv][row * 16 + (((n1r >> 1) + row) & 7) * 2 + (n1r & 1)];
    }

    // ---- step 3a: E = idft16 over c1 ----
    float2 E[16];
    idft16(E, D);

    // ---- step 3b: E[v1] *= W64^{v1*q} (chained; base selected by q) ----
    {
        float2 bq = (q == 0) ? float2{1.0f, 0.0f}
                  : (q == 1) ? float2{0.99518472667219693f, 0.09801714032956060f}
                  : (q == 2) ? float2{0.98078528040323044f, 0.19509032201612827f}
                             : float2{0.95694033573220886f, 0.29028467725446237f};
        float2 w = bq;
        E[1] = cmul(E[1], w);
        #pragma unroll
        for (int v1 = 2; v1 < 16; ++v1) { w = cmul(w, bq); E[v1] = cmul(E[v1], w); }
    }

    // ---- step 3c: cross-lane idft4 over q + window + bf16 plane store ----
    unsigned short* Yb = Y + ((size_t)(b * 4 + (t & 3))) * TOTALP + t * HOPSZ;
    const float sc = 1.0f / 2048.0f;
    const int v2 = ((q & 1) << 1) | (q >> 1);          // bitrev2(q)
    const int nbase = n1r + (v2 << 8);
    #pragma unroll
    for (int v1 = 0; v1 < 16; ++v1) {
        float2 mine = E[v1];
        float2 oth  = float2{__shfl_xor(mine.x, 32), __shfl_xor(mine.y, 32)};
        float2 G    = (lane < 32) ? cadd(mine, oth) : csub(oth, mine);
        float2 o2   = float2{__shfl_xor(G.x, 16), __shfl_xor(G.y, 16)};
        float2 res;
        if (q == 0)      res = cadd(G, o2);                         // E+ + O+   -> v2=0
        else if (q == 1) res = csub(o2, G);                         // E+ - O+   -> v2=2
        else if (q == 2) res = float2{G.x - o2.y, G.y + o2.x};      // E- + iO-  -> v2=1
        else             res = float2{o2.x + G.y, o2.y - G.x};      // E- - iO-  -> v2=3
        const int n = nbase + (v1 << 4);
        const float2 wp = wt[n];
        unsigned pack = ((unsigned)f2bf(res.y * sc * wp.y) << 16)
                      |  (unsigned)f2bf(res.x * sc * wp.x);
        *(unsigned*)(Yb + 2 * n) = pack;
    }
}

// ---------------- final pass: gather 4 planes, divide by window-sumsquare ---
__global__ __launch_bounds__(256) void final_pass(
    const unsigned short* __restrict__ Y,    // [BATCH][4][TOTALP]
    const float2*         __restrict__ wt,   // window pairs
    float*                __restrict__ out)  // [BATCH][OUTLEN]
{
    const int tx = blockIdx.x * 256 + threadIdx.x;
    if (tx >= OUTLEN / 8) return;
    const int b  = blockIdx.y;
    const int n0 = tx * 8;
    const int p0 = n0 + 1024;
    int tmin = (p0 - 1536) >> 9;  if (tmin < 0) tmin = 0;
    int tmax = p0 >> 9;           if (tmax > TFRAMES - 1) tmax = TFRAMES - 1;

    float acc[8], ws[8];
    #pragma unroll
    for (int j = 0; j < 8; ++j) { acc[j] = 0.0f; ws[j] = 0.0f; }

    for (int t = tmin; t <= tmax; ++t) {
        const int a0 = p0 - t * HOPSZ;        // 8-run fully inside [0,2048)
        const uint4 pv = *(const uint4*)(Y + ((size_t)(b * 4 + (t & 3))) * TOTALP + p0);
        const unsigned pw[4] = {pv.x, pv.y, pv.z, pv.w};
        #pragma unroll
        for (int j = 0; j < 4; ++j) {
            acc[2 * j]     += bf2f((unsigned short)(pw[j] & 0xffffu));
            acc[2 * j + 1] += bf2f((unsigned short)(pw[j] >> 16));
        }
        #pragma unroll
        for (int j = 0; j < 4; ++j) {
            float2 w = wt[(a0 >> 1) + j];     // (win[a0+2j], win[a0+2j+1])
            ws[2 * j]     += w.x * w.x;
            ws[2 * j + 1] += w.y * w.y;
        }
    }
    float r[8];
    #pragma unroll
    for (int j = 0; j < 8; ++j) r[j] = acc[j] / fmaxf(ws[j], 1e-8f);
    float4* o = (float4*)(out + (size_t)b * OUTLEN + n0);
    o[0] = float4{r[0], r[1], r[2], r[3]};
    o[1] = float4{r[4], r[5], r[6], r[7]};
}

// ---------------- launch -----------------------------------------------------
extern "C" void kernel_launch(void* const* d_in, const int* in_sizes, int n_in,
                              void* d_out, int out_size, void* d_ws, size_t ws_size,
                              hipStream_t stream) {
    const float* re = (const float*)d_in[0];
    const float* im = (const float*)d_in[1];
    float* out = (float*)d_out;

    char* ws = (char*)d_ws;
    unsigned short* Y  = (unsigned short*)(ws);            // 8*4*1050112*2 = 67,207,168 B
    float2*         wt = (float2*)       (ws + 67207168);  // 1024*8 = 8,192 B

    build_tabs<<<dim3(4),          256, 0, stream>>>(wt);
    fft_frames<<<dim3(MROWS / 4),  256, 0, stream>>>(re, im, wt, Y);
    final_pass<<<dim3(512, BATCH), 256, 0, stream>>>(Y, wt, out);
}

// Round 11
// 76.411 us; speedup vs baseline: 1.0312x; 1.0312x over previous
//
#include <hip/hip_runtime.h>

// ---------------- problem constants ----------------
#define NFFT    2048
#define HOPSZ   512
#define BATCH   8
#define TFRAMES 2048
#define FBINS   1025
#define OUTLEN  1048064           // HOP*(T-1)
#define TOTALP  1050112           // NFFT + HOP*(T-1)
#define MROWS   16384             // BATCH*TFRAMES

__device__ __forceinline__ float bf2f(unsigned short h) {
    return __uint_as_float(((unsigned)h) << 16);
}

__device__ __forceinline__ float2 cmul(float2 a, float2 b) {
    return float2{a.x * b.x - a.y * b.y, a.x * b.y + a.y * b.x};
}
__device__ __forceinline__ float2 cadd(float2 a, float2 b) { return float2{a.x + b.x, a.y + b.y}; }
__device__ __forceinline__ float2 csub(float2 a, float2 b) { return float2{a.x - b.x, a.y - b.y}; }
__device__ __forceinline__ float2 cjmul(float2 a) { return float2{-a.y, a.x}; }   // i*a

// inverse DFT-4: y[r] = sum_j x[j] * i^{r j}
#define IDFT4(y0, y1, y2, y3, x0, x1, x2, x3) do {                         \
    float2 t0 = cadd(x0, x2), t1 = csub(x0, x2);                           \
    float2 t2 = cadd(x1, x3), t3 = cjmul(csub(x1, x3));                    \
    y0 = cadd(t0, t2); y2 = csub(t0, t2);                                  \
    y1 = cadd(t1, t3); y3 = csub(t1, t3); } while (0)

// inverse DFT-16 (radix-4 x radix-4, four-step)
__device__ __forceinline__ void idft16(float2* y, const float2* x) {
    const float c1 = 0.92387953251128674f, s1 = 0.38268343236508977f;   // cos/sin pi/8
    const float r2 = 0.70710678118654752f;
    float2 A[16];
    #pragma unroll
    for (int jb = 0; jb < 4; ++jb)
        IDFT4(A[jb * 4 + 0], A[jb * 4 + 1], A[jb * 4 + 2], A[jb * 4 + 3],
              x[jb], x[4 + jb], x[8 + jb], x[12 + jb]);
    A[4 + 1]  = cmul(A[4 + 1],  float2{c1, s1});
    A[4 + 2]  = cmul(A[4 + 2],  float2{r2, r2});
    A[4 + 3]  = cmul(A[4 + 3],  float2{s1, c1});
    A[8 + 1]  = cmul(A[8 + 1],  float2{r2, r2});
    A[8 + 2]  = cjmul(A[8 + 2]);
    A[8 + 3]  = cmul(A[8 + 3],  float2{-r2, r2});
    A[12 + 1] = cmul(A[12 + 1], float2{s1, c1});
    A[12 + 2] = cmul(A[12 + 2], float2{-r2, r2});
    A[12 + 3] = cmul(A[12 + 3], float2{-c1, -s1});
    #pragma unroll
    for (int ra = 0; ra < 4; ++ra)
        IDFT4(y[ra], y[ra + 4], y[ra + 8], y[ra + 12],
              A[ra], A[4 + ra], A[8 + ra], A[12 + ra]);
}

// ---------------- window table: wt[n] = (win[2n], win[2n+1]) * (1/2048) -----
__global__ void build_tabs(float2* __restrict__ wt) {
    int n = blockIdx.x * 256 + threadIdx.x;
    const float s = 1.0f / 2048.0f;
    if (n < 1024)
        wt[n] = float2{(0.5f - 0.5f * cospif((float)(2 * n)     * (1.0f / 1024.0f))) * s,
                       (0.5f - 0.5f * cospif((float)(2 * n + 1) * (1.0f / 1024.0f))) * s};
}

// ---------------- per-frame irfft: wave-per-frame four-step register FFT ----
// 1024 = 16 x 64 Bailey four-step (verified r10). Barrier-free: the transpose
// buffer is PER-WAVE, so a s_waitcnt lgkmcnt(0) (+sched_barrier) replaces
// __syncthreads. 128-thread blocks (2 waves, 16KB LDS) for occupancy.
__global__ __launch_bounds__(128) void fft_frames(
    const float* __restrict__ re, const float* __restrict__ im,
    const float2* __restrict__ wt,
    unsigned short* __restrict__ Y)          // [BATCH][4][TOTALP] bf16
{
    __shared__ float2 tb[2][1024];           // 8KB per wave

    const int tid   = threadIdx.x;
    const int lane  = tid & 63;
    const int wv    = tid >> 6;
    const int frame = blockIdx.x * 2 + wv;
    const int b     = frame >> 11;
    const int t     = frame & (TFRAMES - 1);
    const float* rr = re + (size_t)frame * FBINS;
    const float* ii = im + (size_t)frame * FBINS;

    // per-lane twiddle bases (only transcendentals in the kernel)
    const float2 packb = float2{cospif((float)lane * (1.0f / 1024.0f)),
                                sinpif((float)lane * (1.0f / 1024.0f))};  // e^{i pi l/1024}
    const float2 base2 = cmul(packb, packb);                              // e^{2pi i l/1024}

    // e^{i pi k1/16}, k1 = 0..15 (compile-time immediates after unroll)
    const float wkc[16] = { 1.0f, 0.98078528040323044f, 0.92387953251128674f, 0.83146961230254524f,
                            0.70710678118654752f, 0.55557023301960222f, 0.38268343236508977f, 0.19509032201612827f,
                            0.0f, -0.19509032201612827f, -0.38268343236508977f, -0.55557023301960222f,
                            -0.70710678118654752f, -0.83146961230254524f, -0.92387953251128674f, -0.98078528040323044f };
    const float wks[16] = { 0.0f, 0.19509032201612827f, 0.38268343236508977f, 0.55557023301960222f,
                            0.70710678118654752f, 0.83146961230254524f, 0.92387953251128674f, 0.98078528040323044f,
                            1.0f, 0.98078528040323044f, 0.92387953251128674f, 0.83146961230254524f,
                            0.70710678118654752f, 0.55557023301960222f, 0.38268343236508977f, 0.19509032201612827f };

    // ---- pack: zz[k1] = Z[64*k1 + lane] ----
    float2 zz[16];
    #pragma unroll
    for (int k1 = 0; k1 < 16; ++k1) {
        const int m = 64 * k1 + lane;
        float Xr = rr[m],        Xi = ii[m];
        float Cr = rr[1024 - m], Ni = ii[1024 - m];
        float2 W = cmul(packb, float2{wkc[k1], wks[k1]});   // e^{i pi m/1024}
        float Er = Xr + Cr, Ei = Xi - Ni;
        float Or = Xr - Cr, Oi = Xi + Ni;
        float2 z = float2{Er - (W.x * Oi + W.y * Or), Ei + (W.x * Or - W.y * Oi)};
        if (k1 == 0 && lane == 0)                           // m == 0: im parts drop
            z = float2{Xr + Cr, Xr - Cr};
        zz[k1] = z;
    }

    // ---- step 1: A = idft16 over k1 ----
    float2 A[16];
    idft16(A, zz);

    // ---- step 2: A[n1] *= W1024^{n1*lane} (chained) ----
    {
        float2 w = base2;
        A[1] = cmul(A[1], w);
        #pragma unroll
        for (int n1 = 2; n1 < 16; ++n1) { w = cmul(w, base2); A[n1] = cmul(A[n1], w); }
    }

    // ---- transpose write: row=lane, 8 x float4, chunk-rotated ----
    {
        float4* rowp = (float4*)&tb[wv][lane * 16];
        #pragma unroll
        for (int j = 0; j < 8; ++j) {
            float2 e = A[2 * j], o = A[2 * j + 1];
            rowp[(j + lane) & 7] = float4{e.x, e.y, o.x, o.y};
        }
    }
    // per-wave LDS dependence only: wait our own writes, fence the scheduler
    asm volatile("s_waitcnt lgkmcnt(0)" ::: "memory");
    __builtin_amdgcn_sched_barrier(0);

    // ---- regroup read: lane = (q = lane>>4, n1r = lane&15); D[c1] = B[4c1+q][n1r]
    const int q   = lane >> 4;
    const int n1r = lane & 15;
    float2 D[16];
    #pragma unroll
    for (int c1 = 0; c1 < 16; ++c1) {
        const int row = 4 * c1 + q;
        D[c1] = tb[wv][row * 16 + (((n1r >> 1) + row) & 7) * 2 + (n1r & 1)];
    }

    // ---- step 3a: E = idft16 over c1 ----
    float2 E[16];
    idft16(E, D);

    // ---- step 3b: E[v1] *= W64^{v1*q} (chained; base selected by q) ----
    {
        float2 bq = (q == 0) ? float2{1.0f, 0.0f}
                  : (q == 1) ? float2{0.99518472667219693f, 0.09801714032956060f}
                  : (q == 2) ? float2{0.98078528040323044f, 0.19509032201612827f}
                             : float2{0.95694033573220886f, 0.29028467725446237f};
        float2 w = bq;
        E[1] = cmul(E[1], w);
        #pragma unroll
        for (int v1 = 2; v1 < 16; ++v1) { w = cmul(w, bq); E[v1] = cmul(E[v1], w); }
    }

    // ---- step 3c: cross-lane idft4 over q + window + bf16 plane store ----
    unsigned short* Yb = Y + ((size_t)(b * 4 + (t & 3))) * TOTALP + t * HOPSZ;
    const int v2 = ((q & 1) << 1) | (q >> 1);          // bitrev2(q)
    const int nbase = n1r + (v2 << 8);
    #pragma unroll
    for (int v1 = 0; v1 < 16; ++v1) {
        float2 mine = E[v1];
        float2 oth  = float2{__shfl_xor(mine.x, 32), __shfl_xor(mine.y, 32)};
        float2 G    = (lane < 32) ? cadd(mine, oth) : csub(oth, mine);
        float2 o2   = float2{__shfl_xor(G.x, 16), __shfl_xor(G.y, 16)};
        float2 res;
        if (q == 0)      res = cadd(G, o2);                         // E+ + O+   -> v2=0
        else if (q == 1) res = csub(o2, G);                         // E+ - O+   -> v2=2
        else if (q == 2) res = float2{G.x - o2.y, G.y + o2.x};      // E- + iO-  -> v2=1
        else             res = float2{o2.x + G.y, o2.y - G.x};      // E- - iO-  -> v2=3
        const int n = nbase + (v1 << 4);
        const float2 wp = wt[n];                // window * (1/2048)
        const float lo = res.x * wp.x, hi = res.y * wp.y;
        unsigned pack;
        asm("v_cvt_pk_bf16_f32 %0, %1, %2" : "=v"(pack) : "v"(lo), "v"(hi));
        *(unsigned*)(Yb + 2 * n) = pack;
    }
}

// ---------------- final pass: gather 4 planes, divide by window-sumsquare ---
// wt is scaled by s=1/2048: Y holds x*win exactly; ws = s^2 * sum(win^2),
// so out = acc * s^2 / ws.
__global__ __launch_bounds__(256) void final_pass(
    const unsigned short* __restrict__ Y,    // [BATCH][4][TOTALP]
    const float2*         __restrict__ wt,   // window pairs * s
    float*                __restrict__ out)  // [BATCH][OUTLEN]
{
    const int tx = blockIdx.x * 256 + threadIdx.x;
    if (tx >= OUTLEN / 8) return;
    const int b  = blockIdx.y;
    const int n0 = tx * 8;
    const int p0 = n0 + 1024;
    int tmin = (p0 - 1536) >> 9;  if (tmin < 0) tmin = 0;
    int tmax = p0 >> 9;           if (tmax > TFRAMES - 1) tmax = TFRAMES - 1;

    float acc[8], ws[8];
    #pragma unroll
    for (int j = 0; j < 8; ++j) { acc[j] = 0.0f; ws[j] = 0.0f; }

    for (int t = tmin; t <= tmax; ++t) {
        const int a0 = p0 - t * HOPSZ;        // 8-run fully inside [0,2048)
        const uint4 pv = *(const uint4*)(Y + ((size_t)(b * 4 + (t & 3))) * TOTALP + p0);
        const unsigned pw[4] = {pv.x, pv.y, pv.z, pv.w};
        #pragma unroll
        for (int j = 0; j < 4; ++j) {
            acc[2 * j]     += bf2f((unsigned short)(pw[j] & 0xffffu));
            acc[2 * j + 1] += bf2f((unsigned short)(pw[j] >> 16));
        }
        #pragma unroll
        for (int j = 0; j < 4; ++j) {
            float2 w = wt[(a0 >> 1) + j];     // (win[a0+2j], win[a0+2j+1]) * s
            ws[2 * j]     += w.x * w.x;
            ws[2 * j + 1] += w.y * w.y;
        }
    }
    const float S2 = (1.0f / 2048.0f) * (1.0f / 2048.0f);
    float r[8];
    #pragma unroll
    for (int j = 0; j < 8; ++j) r[j] = acc[j] * S2 / fmaxf(ws[j], 2.4e-15f);
    float4* o = (float4*)(out + (size_t)b * OUTLEN + n0);
    o[0] = float4{r[0], r[1], r[2], r[3]};
    o[1] = float4{r[4], r[5], r[6], r[7]};
}

// ---------------- launch -----------------------------------------------------
extern "C" void kernel_launch(void* const* d_in, const int* in_sizes, int n_in,
                              void* d_out, int out_size, void* d_ws, size_t ws_size,
                              hipStream_t stream) {
    const float* re = (const float*)d_in[0];
    const float* im = (const float*)d_in[1];
    float* out = (float*)d_out;

    char* ws = (char*)d_ws;
    unsigned short* Y  = (unsigned short*)(ws);            // 8*4*1050112*2 = 67,207,168 B
    float2*         wt = (float2*)       (ws + 67207168);  // 1024*8 = 8,192 B

    build_tabs<<<dim3(4),          256, 0, stream>>>(wt);
    fft_frames<<<dim3(MROWS / 2),  128, 0, stream>>>(re, im, wt, Y);
    final_pass<<<dim3(512, BATCH), 256, 0, stream>>>(Y, wt, out);
}